// Round 6
// baseline (1092.148 us; speedup 1.0000x reference)
//
#include <hip/hip_runtime.h>
#include <hip/hip_fp16.h>

// Fixed problem shape
#define TOK   64
#define INF   4096
#define OUTF  11008
#define NUMEL (OUTF * INF)        // 45088768
#define NSLC  (NUMEL / 64)        // 704512 64-element slices
#define NBLK  (OUTF / 16)         // 688 N-tiles
#define KSPL  4                   // K-split -> 2752 blocks, K=1024 each
#define NCH   4                   // per-wave chunks of 64 K (wave K = 256)
#define OUTN  (TOK * OUTF)        // 704512 output elems

// Harness dtypes: fp16 arrays arrive as fp32; ints as int32; output fp32.
typedef __attribute__((ext_vector_type(8))) _Float16 half8;
typedef __attribute__((ext_vector_type(4))) _Float16 half4;
typedef __attribute__((ext_vector_type(4))) float floatx4;
typedef __attribute__((ext_vector_type(4), aligned(4))) int int4u;   // dword-aligned dwordx4
typedef __attribute__((ext_vector_type(4))) int int4a;               // 16B-aligned dwordx4

// Wave-private tile row stride: 64 + 8 fp16 = 144 B. 16B-aligned; both the
// staging ds_write_b128 (16B-unit w = (srow+2*ssub) mod 8, 8 lanes each) and
// the MFMA ds_read_b128 (w = (ln+quad) mod 8, 8 lanes each) spread evenly
// over the 8 bank windows -> minimum-cycle LDS access.
#define TPAD 72

// ---------------------------------------------------------------------------
// Precompute (unchanged): (a) x fp32 -> fp16 (512 KB, L2-resident GEMM A),
// (b) per-64-slice meta[s] = {c0 = lower_bound(fp16_pos, 64*s),
//     outlier mask lo, mask hi, pad} — one 16 B record.
// ---------------------------------------------------------------------------
__global__ __launch_bounds__(256) void precompute_kernel(
    const float* __restrict__ x, const int* __restrict__ fppos, int nf,
    _Float16* __restrict__ x16, int* __restrict__ meta) {
  const int t = blockIdx.x * 256 + threadIdx.x;
  if (t < (TOK * INF) / 4) {
    const floatx4 f = *(const floatx4*)&x[t * 4];
    half4 h;
    h[0] = (_Float16)f[0]; h[1] = (_Float16)f[1];
    h[2] = (_Float16)f[2]; h[3] = (_Float16)f[3];
    *(half4*)&x16[t * 4] = h;
  }
  if (t < NSLC) {
    const int target = t << 6;
    int lo = 0, hi = nf;
    while (lo < hi) {
      const int mid = (lo + hi) >> 1;
      if (fppos[mid] < target) lo = mid + 1; else hi = mid;
    }
    unsigned long long mask = 0ull;
    int j = lo;
    while (j < nf) {                 // mean 0.17 iters; P(>2) ~ 1e-4
      const int d = fppos[j] - target;
      if (d >= 64) break;
      mask |= 1ull << d;
      ++j;
    }
    int4a mv;
    mv[0] = lo;
    mv[1] = (int)(unsigned)(mask & 0xffffffffu);
    mv[2] = (int)(unsigned)(mask >> 32);
    mv[3] = 0;
    *(int4a*)&meta[t * 4] = mv;
  }
}

// ---------------------------------------------------------------------------
// window16: from one slice meta record, the compacted indices / 8-bit outlier
// windows for a lane's TWO adjacent 8-slots [p0,p0+8),[p0+8,p0+16).
// off = p0&63 in {0,16,32,48}: windows never straddle the 32-bit halves.
// i0b = i0a + 8 - popc(m8a): slot B's own compacted start -> both slots use
// plain register windows l[0..7], l[8..15] with NO shifting.
// ---------------------------------------------------------------------------
__device__ __forceinline__ void window16(const int p0, const int4a mv,
                                         int& i0a, unsigned& m8a,
                                         int& i0b, unsigned& m8b) {
  const unsigned mlo = (unsigned)mv[1];
  const unsigned mhi = (unsigned)mv[2];
  const int off = p0 & 63;
  const unsigned w32 = (off & 32) ? mhi : mlo;
  const unsigned m16 = (off & 16) ? (w32 >> 16) : (w32 & 0xffffu);
  int ltb = 0;
  if (off & 32) ltb += __popc(mlo);
  if (off & 16) ltb += __popc(w32 & 0xffffu);
  m8a = m16 & 0xffu;
  m8b = (m16 >> 8) & 0xffu;
  i0a = p0 - mv[0] - ltb;
  i0b = i0a + 8 - __popc(m8a);
}

// ---------------------------------------------------------------------------
// finish_slot (verbatim verified R2-R5): combine prefetched i8 dwords + rare
// fp16 outliers -> half8. fpdat index of first outlier >= p0 is p0 - i0.
// ---------------------------------------------------------------------------
__device__ __forceinline__ half8 finish_slot(
    const unsigned m8, const int i0, const int p0, const float s,
    const int (&l)[8], const int* __restrict__ i8,
    const float* __restrict__ fpdat, const int n8) {
  const int f = (int)m8;
  float ov[8];
#pragma unroll
  for (int e = 0; e < 8; ++e) ov[e] = 0.f;
  if (f) {
    int fi = p0 - i0;  // c0 + (#outliers below p0)
#pragma unroll
    for (int e = 0; e < 8; ++e) {
      if ((f >> e) & 1) { ov[e] = fpdat[fi]; ++fi; }
    }
  }

  half8 oh;
  if (i0 + 8 <= n8) {
    if (f == 0) {
#pragma unroll
      for (int e = 0; e < 8; ++e) oh[e] = (_Float16)((float)l[e] * s);
    } else {
      int q = 0;
#pragma unroll
      for (int e = 0; e < 8; ++e) {
        const int flg = (f >> e) & 1;
        int lv = l[0];
#pragma unroll
        for (int qq = 1; qq < 8; ++qq) lv = (q == qq) ? l[qq] : lv;
        oh[e] = flg ? (_Float16)ov[e] : (_Float16)((float)lv * s);
        q += 1 - flg;
      }
    }
  } else {
    // Array-tail path (last few global slots only): clamped scalar loads.
    int c = 0;
    const int m = n8 - 1;
#pragma unroll
    for (int e = 0; e < 8; ++e) {
      const int flg = (f >> e) & 1;
      int idx = i0 + e - c;
      idx = idx < 0 ? 0 : (idx > m ? m : idx);
      oh[e] = flg ? (_Float16)ov[e] : (_Float16)((float)i8[idx] * s);
      c += flg;
    }
  }
  return oh;
}

// ---------------------------------------------------------------------------
// Fused GEMM v6 — ZERO main-loop barriers (wave-private pipelined tiles).
// R5 post-mortem: __syncthreads() emits s_waitcnt vmcnt(0) before s_barrier
// -> every chunk barrier DRAINED the prefetch queue; all barrier-per-chunk
// variants (R2/R3/R5) pin at ~110-120 us with ~12% load duty. v6: wave w
// owns the disjoint K-slice [kbas+w*256,+256) as 4 chunks of 64, staged into
// wave-PRIVATE double-buffered LDS (16x64, TPAD rows). No cross-wave sharing
// -> no barrier until the epilogue reduce -> compiler emits counted waitcnts
// and i8(c+1)/meta(c+2) stay in flight across the full iteration.
// Staging map: lane=(srow=lane>>2, ssub=lane&3) reads 16 consecutive values;
// 4-lane groups = 256 B contiguous i8 (coalesced). Scale: one load per block
// (slice scale == scales[row*4+kq] for the whole wave-K). Epilogue: LDS red
// reduce + partial store + tiny reduce kernel (unchanged, R5-verified).
// mfma_f32_16x16x32_f16 mapping verified R1-R5 (absmax 0.03125 pass).
// ---------------------------------------------------------------------------
__global__ __launch_bounds__(256, 4) void gemm_fused(
    const _Float16* __restrict__ x16, const int* __restrict__ i8,
    const float* __restrict__ fpdat, const float* __restrict__ scales,
    const int* __restrict__ meta, float* __restrict__ part, const int n8) {
  __shared__ __attribute__((aligned(16))) char smem[4 * 2 * 16 * TPAD * 2];  // 18.4 KB
  _Float16 (* __restrict__ tiles)[2][16][TPAD] = (_Float16 (*)[2][16][TPAD])smem;
  float* red = (float*)smem;  // 16 KB, aliases tiles; used after final barrier

  const int tid  = threadIdx.x;
  const int wave = tid >> 6;
  const int lane = tid & 63;
  const int nt   = blockIdx.x >> 2;
  const int kq   = blockIdx.x & 3;
  const int n0   = nt << 4;
  const int kbas = kq * 1024 + wave * 256;  // this wave's K base

  // Staging roles
  const int srow  = lane >> 2;          // local row 0..15
  const int ssub  = lane & 3;           // 16-value sub-run within 64-chunk
  const int prow  = n0 + srow;
  const int pbase = prow * INF + kbas;  // positioned base of this row's wave-K
  const float s   = scales[prow * 4 + kq];  // block-constant quant scale

  // MFMA roles
  const int ln   = lane & 15;
  const int quad = lane >> 4;

  int4a    mreg[2];      // meta(c) in bank c&1
  int      l8[2][16];    // prefetched i8 dwords, bank c&1
  int      i0a[2], i0b[2];
  unsigned m8a[2], m8b[2];

  // ---- Prologue: meta(0), meta(1); window+issue i8(0) ----
  mreg[0] = *(const int4a*)&meta[(pbase >> 6) * 4];
  mreg[1] = *(const int4a*)&meta[((pbase + 64) >> 6) * 4];
  {
    const int p0 = pbase + ssub * 16;
    window16(p0, mreg[0], i0a[0], m8a[0], i0b[0], m8b[0]);
    if (i0a[0] + 8 <= n8) {
      *(int4u*)&l8[0][0] = *(const int4u*)&i8[i0a[0]];
      *(int4u*)&l8[0][4] = *(const int4u*)&i8[i0a[0] + 4];
    }
    if (i0b[0] + 8 <= n8) {
      *(int4u*)&l8[0][8]  = *(const int4u*)&i8[i0b[0]];
      *(int4u*)&l8[0][12] = *(const int4u*)&i8[i0b[0] + 4];
    }
  }

  floatx4 acc0 = {0,0,0,0}, acc1 = {0,0,0,0}, acc2 = {0,0,0,0}, acc3 = {0,0,0,0};

#pragma unroll
  for (int c = 0; c < NCH; ++c) {
    const int bk = c & 1;        // constant under full unroll (no scratch)
    const int nb = bk ^ 1;

    // ---- Issue: window+i8 for c+1 (meta resident), meta for c+2 ----
    // No barrier follows -> these stay in flight across finish+MFMA.
    if (c + 1 < NCH) {
      const int p0 = pbase + (c + 1) * 64 + ssub * 16;
      window16(p0, mreg[nb], i0a[nb], m8a[nb], i0b[nb], m8b[nb]);
      if (i0a[nb] + 8 <= n8) {
        *(int4u*)&l8[nb][0] = *(const int4u*)&i8[i0a[nb]];
        *(int4u*)&l8[nb][4] = *(const int4u*)&i8[i0a[nb] + 4];
      }
      if (i0b[nb] + 8 <= n8) {
        *(int4u*)&l8[nb][8]  = *(const int4u*)&i8[i0b[nb]];
        *(int4u*)&l8[nb][12] = *(const int4u*)&i8[i0b[nb] + 4];
      }
      if (c + 2 < NCH)
        mreg[bk] = *(const int4a*)&meta[((pbase + (c + 2) * 64) >> 6) * 4];
    }

    // ---- Finish chunk c (waits only its own i8, issued 1 iter ago) ----
    {
      const int p0 = pbase + c * 64 + ssub * 16;
      const half8 ha = finish_slot(m8a[bk], i0a[bk], p0, s,
                                   *(const int (*)[8])&l8[bk][0], i8, fpdat, n8);
      const half8 hb = finish_slot(m8b[bk], i0b[bk], p0 + 8, s,
                                   *(const int (*)[8])&l8[bk][8], i8, fpdat, n8);
      *(half8*)&tiles[wave][bk][srow][ssub * 16]     = ha;
      *(half8*)&tiles[wave][bk][srow][ssub * 16 + 8] = hb;
    }

    // ---- MFMA chunk c from own tile (lgkm-counted wait, wave-local) ----
    {
      const _Float16* ap = &x16[ln * INF + kbas + c * 64 + quad * 8];
      const _Float16* bp = &tiles[wave][bk][ln][quad * 8];
#pragma unroll
      for (int st = 0; st < 2; ++st) {
        const int ko = st * 32;
        const half8 bh = *(const half8*)&bp[ko];          // ds_read_b128
        const half8 a0 = *(const half8*)&ap[ko];
        const half8 a1 = *(const half8*)&ap[16 * INF + ko];
        const half8 a2 = *(const half8*)&ap[32 * INF + ko];
        const half8 a3 = *(const half8*)&ap[48 * INF + ko];
        acc0 = __builtin_amdgcn_mfma_f32_16x16x32_f16(a0, bh, acc0, 0, 0, 0);
        acc1 = __builtin_amdgcn_mfma_f32_16x16x32_f16(a1, bh, acc1, 0, 0, 0);
        acc2 = __builtin_amdgcn_mfma_f32_16x16x32_f16(a2, bh, acc2, 0, 0, 0);
        acc3 = __builtin_amdgcn_mfma_f32_16x16x32_f16(a3, bh, acc3, 0, 0, 0);
      }
    }
  }

  // ---- Epilogue: the ONLY barriers. All waves done reading their tiles
  // before red (aliasing smem) is written. ----
  __syncthreads();

  const int mb = quad * 4;
#pragma unroll
  for (int i = 0; i < 4; ++i) red[wave * 1024 + (mb + i)      * 16 + ln] = acc0[i];
#pragma unroll
  for (int i = 0; i < 4; ++i) red[wave * 1024 + (16 + mb + i) * 16 + ln] = acc1[i];
#pragma unroll
  for (int i = 0; i < 4; ++i) red[wave * 1024 + (32 + mb + i) * 16 + ln] = acc2[i];
#pragma unroll
  for (int i = 0; i < 4; ++i) red[wave * 1024 + (48 + mb + i) * 16 + ln] = acc3[i];
  __syncthreads();

  // ---- Plain partial store ----
  float* pp = &part[(size_t)kq * OUTN];
#pragma unroll
  for (int c2 = 0; c2 < 4; ++c2) {
    const int cell = tid + c2 * 256;  // 1024 cells = 64 m x 16 n
    const int mm = cell >> 4, nn = cell & 15;
    pp[mm * OUTF + n0 + nn] =
        red[cell] + red[1024 + cell] + red[2048 + cell] + red[3072 + cell];
  }
}

// ---------------------------------------------------------------------------
// Reduce: out = sum_kq part[kq] + bias. 11.3 MB read + 2.8 MB write ~ 3 us.
// ---------------------------------------------------------------------------
__global__ __launch_bounds__(256) void reduce_kernel(
    const float* __restrict__ part, const float* __restrict__ bias,
    float* __restrict__ out) {
  const int t  = blockIdx.x * 256 + threadIdx.x;  // 688*256 = 176128 exact
  const int i4 = t * 4;
  floatx4 a = *(const floatx4*)&part[i4];
#pragma unroll
  for (int k = 1; k < KSPL; ++k) {
    const floatx4 b = *(const floatx4*)&part[(size_t)k * OUTN + i4];
    a[0] += b[0]; a[1] += b[1]; a[2] += b[2]; a[3] += b[3];
  }
  const int nn = i4 % OUTF;  // OUTF % 4 == 0: float4 never straddles rows
  const floatx4 bb = *(const floatx4*)&bias[nn];
  a[0] += bb[0]; a[1] += bb[1]; a[2] += bb[2]; a[3] += bb[3];
  *(floatx4*)&out[i4] = a;
}

// ---------------------------------------------------------------------------
// Inputs: 0 x(fp32) 1 int8_data(i32) 2 fp16_data(fp32) 3 scales(fp32)
// 4 bias(fp32) 5 int8_pos(UNUSED) 6 fp16_pos(i32) 7 block_idx(UNUSED)
// ws: x16 (512 KB) | meta (11.3 MB) | part (11.3 MB)
// ---------------------------------------------------------------------------
extern "C" void kernel_launch(void* const* d_in, const int* in_sizes, int n_in,
                              void* d_out, int out_size, void* d_ws,
                              size_t ws_size, hipStream_t stream) {
  const float* x      = (const float*)d_in[0];
  const int*   i8     = (const int*)d_in[1];
  const float* fpdat  = (const float*)d_in[2];
  const float* scales = (const float*)d_in[3];
  const float* bias   = (const float*)d_in[4];
  const int*   fppos  = (const int*)d_in[6];

  char* wsp = (char*)d_ws;
  _Float16* x16  = (_Float16*)wsp;
  int*      meta = (int*)(wsp + (size_t)TOK * INF * sizeof(_Float16));
  float*    part = (float*)(wsp + (size_t)TOK * INF * sizeof(_Float16)
                                + (size_t)NSLC * 16);
  float*    out  = (float*)d_out;

  const int n8 = in_sizes[1];
  const int nf = in_sizes[2];

  precompute_kernel<<<NSLC / 256, 256, 0, stream>>>(x, fppos, nf, x16, meta);
  gemm_fused<<<NBLK * KSPL, 256, 0, stream>>>(x16, i8, fpdat, scales, meta,
                                              part, n8);
  reduce_kernel<<<OUTN / (4 * 256), 256, 0, stream>>>(part, bias, out);
}

// Round 7
// 450.773 us; speedup vs baseline: 2.4228x; 2.4228x over previous
//
#include <hip/hip_runtime.h>
#include <hip/hip_fp16.h>

// Fixed problem shape
#define TOK   64
#define INF   4096
#define OUTF  11008
#define NUMEL (OUTF * INF)        // 45088768
#define NSLC  (NUMEL / 64)        // 704512 64-element slices
#define NBLK  (OUTF / 16)         // 688 N-tiles
#define KSPL  4                   // K-split -> 2752 blocks, K=1024 each
#define OUTN  (TOK * OUTF)        // 704512 output elems

// Harness dtypes: fp16 arrays arrive as fp32; ints as int32; output fp32.
typedef __attribute__((ext_vector_type(8))) _Float16 half8;
typedef __attribute__((ext_vector_type(4))) _Float16 half4;
typedef __attribute__((ext_vector_type(4))) float floatx4;
typedef __attribute__((ext_vector_type(4), aligned(4))) int int4u;   // dword-aligned dwordx4
typedef __attribute__((ext_vector_type(4))) int int4a;               // 16B-aligned dwordx4

// Wave-private tile row stride: 64 + 8 fp16 = 144 B (16B-aligned; staging
// writes and MFMA reads spread evenly over the 8 16B bank windows).
#define TPAD 72

// ---------------------------------------------------------------------------
// Precompute (unchanged): (a) x fp32 -> fp16 (512 KB, L2-resident GEMM A),
// (b) per-64-slice meta[s] = {c0 = lower_bound(fp16_pos, 64*s),
//     outlier mask lo, mask hi, pad} — one 16 B record.
// ---------------------------------------------------------------------------
__global__ __launch_bounds__(256) void precompute_kernel(
    const float* __restrict__ x, const int* __restrict__ fppos, int nf,
    _Float16* __restrict__ x16, int* __restrict__ meta) {
  const int t = blockIdx.x * 256 + threadIdx.x;
  if (t < (TOK * INF) / 4) {
    const floatx4 f = *(const floatx4*)&x[t * 4];
    half4 h;
    h[0] = (_Float16)f[0]; h[1] = (_Float16)f[1];
    h[2] = (_Float16)f[2]; h[3] = (_Float16)f[3];
    *(half4*)&x16[t * 4] = h;
  }
  if (t < NSLC) {
    const int target = t << 6;
    int lo = 0, hi = nf;
    while (lo < hi) {
      const int mid = (lo + hi) >> 1;
      if (fppos[mid] < target) lo = mid + 1; else hi = mid;
    }
    unsigned long long mask = 0ull;
    int j = lo;
    while (j < nf) {                 // mean 0.17 iters; P(>2) ~ 1e-4
      const int d = fppos[j] - target;
      if (d >= 64) break;
      mask |= 1ull << d;
      ++j;
    }
    int4a mv;
    mv[0] = lo;
    mv[1] = (int)(unsigned)(mask & 0xffffffffu);
    mv[2] = (int)(unsigned)(mask >> 32);
    mv[3] = 0;
    *(int4a*)&meta[t * 4] = mv;
  }
}

// ---------------------------------------------------------------------------
// window16 (R6-verified numerics): compacted indices / 8-bit outlier windows
// for a lane's TWO adjacent 8-slots [p0,p0+8),[p0+8,p0+16).
// off = p0&63 in {0,16,32,48}: windows never straddle the 32-bit halves.
// ---------------------------------------------------------------------------
__device__ __forceinline__ void window16(const int p0, const int4a mv,
                                         int& i0a, unsigned& m8a,
                                         int& i0b, unsigned& m8b) {
  const unsigned mlo = (unsigned)mv[1];
  const unsigned mhi = (unsigned)mv[2];
  const int off = p0 & 63;
  const unsigned w32 = (off & 32) ? mhi : mlo;
  const unsigned m16 = (off & 16) ? (w32 >> 16) : (w32 & 0xffffu);
  int ltb = 0;
  if (off & 32) ltb += __popc(mlo);
  if (off & 16) ltb += __popc(w32 & 0xffffu);
  m8a = m16 & 0xffu;
  m8b = (m16 >> 8) & 0xffu;
  i0a = p0 - mv[0] - ltb;
  i0b = i0a + 8 - __popc(m8a);
}

// ---------------------------------------------------------------------------
// finish_slot (verbatim verified R2-R6): combine prefetched i8 dwords + rare
// fp16 outliers -> half8. fpdat index of first outlier >= p0 is p0 - i0.
// ---------------------------------------------------------------------------
__device__ __forceinline__ half8 finish_slot(
    const unsigned m8, const int i0, const int p0, const float s,
    const int (&l)[8], const int* __restrict__ i8,
    const float* __restrict__ fpdat, const int n8) {
  const int f = (int)m8;
  float ov[8];
#pragma unroll
  for (int e = 0; e < 8; ++e) ov[e] = 0.f;
  if (f) {
    int fi = p0 - i0;  // c0 + (#outliers below p0)
#pragma unroll
    for (int e = 0; e < 8; ++e) {
      if ((f >> e) & 1) { ov[e] = fpdat[fi]; ++fi; }
    }
  }

  half8 oh;
  if (i0 + 8 <= n8) {
    if (f == 0) {
#pragma unroll
      for (int e = 0; e < 8; ++e) oh[e] = (_Float16)((float)l[e] * s);
    } else {
      int q = 0;
#pragma unroll
      for (int e = 0; e < 8; ++e) {
        const int flg = (f >> e) & 1;
        int lv = l[0];
#pragma unroll
        for (int qq = 1; qq < 8; ++qq) lv = (q == qq) ? l[qq] : lv;
        oh[e] = flg ? (_Float16)ov[e] : (_Float16)((float)lv * s);
        q += 1 - flg;
      }
    }
  } else {
    // Array-tail path (last few global slots only): clamped scalar loads.
    int c = 0;
    const int m = n8 - 1;
#pragma unroll
    for (int e = 0; e < 8; ++e) {
      const int flg = (f >> e) & 1;
      int idx = i0 + e - c;
      idx = idx < 0 ? 0 : (idx > m ? m : idx);
      oh[e] = flg ? (_Float16)ov[e] : (_Float16)((float)i8[idx] * s);
      c += flg;
    }
  }
  return oh;
}

// Per-bank prefetch state: two DIRECT 8-int arrays (loaded/passed whole —
// the R4/R5-proven no-spill pattern; no interior-pointer casts).
struct Bank {
  int la[8];
  int lb[8];
  int i0a, i0b;
  unsigned m8a, m8b;
};

// ---------------------------------------------------------------------------
// Fused GEMM v7 — v6's zero-barrier wave-private pipeline, spill-proof.
// R6 post-mortem: mid-array reinterpret casts (&l8[bk][8] as int(*)[8])
// broke SROA -> whole prefetch array in scratch (WRITE_SIZE 1.83 GB, VGPR
// 64 under a 128 cap). v7: Bank struct with direct la/lb arrays; the
// 4-chunk loop is MACRO-unrolled so every bank / LDS-buffer index is
// textually compile-time. Structure unchanged: wave w owns K-slice
// [kbas+w*256,+256) as 4 chunks of 64 staged into wave-private
// double-buffered LDS; NO barrier until the epilogue -> compiler emits
// counted waitcnts and i8(c+1)/meta(c+2) stay in flight across the full
// iteration (the clean test of the R5 barrier-drain theory).
// mfma_f32_16x16x32_f16 mapping verified R1-R6 (absmax 0.03125 pass).
// ---------------------------------------------------------------------------
__global__ __launch_bounds__(256, 4) void gemm_fused(
    const _Float16* __restrict__ x16, const int* __restrict__ i8,
    const float* __restrict__ fpdat, const float* __restrict__ scales,
    const int* __restrict__ meta, float* __restrict__ part, const int n8) {
  __shared__ __attribute__((aligned(16))) char smem[4 * 2 * 16 * TPAD * 2];  // 18.4 KB
  _Float16 (* __restrict__ tiles)[2][16][TPAD] = (_Float16 (*)[2][16][TPAD])smem;
  float* red = (float*)smem;  // 16 KB, aliases tiles; used after final barrier

  const int tid  = threadIdx.x;
  const int wave = tid >> 6;
  const int lane = tid & 63;
  const int nt   = blockIdx.x >> 2;
  const int kq   = blockIdx.x & 3;
  const int n0   = nt << 4;
  const int kbas = kq * 1024 + wave * 256;  // this wave's K base

  // Staging roles: lane=(srow, ssub); 4-lane groups read 256 B contiguous i8.
  const int srow  = lane >> 2;          // local row 0..15
  const int ssub  = lane & 3;           // 16-value sub-run within 64-chunk
  const int prow  = n0 + srow;
  const int pbase = prow * INF + kbas;  // positioned base of this row's wave-K
  const float s   = scales[prow * 4 + kq];  // block-constant quant scale

  // MFMA roles
  const int ln   = lane & 15;
  const int quad = lane >> 4;

#define ISSUE(BNK, P0, MV)                                          \
  do {                                                              \
    window16((P0), (MV), BNK.i0a, BNK.m8a, BNK.i0b, BNK.m8b);       \
    if (BNK.i0a + 8 <= n8) {                                        \
      *(int4u*)&BNK.la[0] = *(const int4u*)&i8[BNK.i0a];            \
      *(int4u*)&BNK.la[4] = *(const int4u*)&i8[BNK.i0a + 4];        \
    }                                                               \
    if (BNK.i0b + 8 <= n8) {                                        \
      *(int4u*)&BNK.lb[0] = *(const int4u*)&i8[BNK.i0b];            \
      *(int4u*)&BNK.lb[4] = *(const int4u*)&i8[BNK.i0b + 4];        \
    }                                                               \
  } while (0)

#define FINISH(BNK, P0, LB)                                                  \
  do {                                                                       \
    const half8 ha_ = finish_slot(BNK.m8a, BNK.i0a, (P0), s, BNK.la,         \
                                  i8, fpdat, n8);                            \
    const half8 hb_ = finish_slot(BNK.m8b, BNK.i0b, (P0) + 8, s, BNK.lb,     \
                                  i8, fpdat, n8);                            \
    *(half8*)&tiles[wave][LB][srow][ssub * 16]     = ha_;                    \
    *(half8*)&tiles[wave][LB][srow][ssub * 16 + 8] = hb_;                    \
  } while (0)

#define MFMA_STEP(CC, LB)                                                    \
  do {                                                                       \
    const _Float16* ap_ = &x16[ln * INF + kbas + (CC) * 64 + quad * 8];      \
    const _Float16* bp_ = &tiles[wave][LB][ln][quad * 8];                    \
    _Pragma("unroll")                                                        \
    for (int st = 0; st < 2; ++st) {                                         \
      const int ko = st * 32;                                                \
      const half8 bh = *(const half8*)&bp_[ko];                              \
      const half8 a0 = *(const half8*)&ap_[ko];                              \
      const half8 a1 = *(const half8*)&ap_[16 * INF + ko];                   \
      const half8 a2 = *(const half8*)&ap_[32 * INF + ko];                   \
      const half8 a3 = *(const half8*)&ap_[48 * INF + ko];                   \
      acc0 = __builtin_amdgcn_mfma_f32_16x16x32_f16(a0, bh, acc0, 0, 0, 0);  \
      acc1 = __builtin_amdgcn_mfma_f32_16x16x32_f16(a1, bh, acc1, 0, 0, 0);  \
      acc2 = __builtin_amdgcn_mfma_f32_16x16x32_f16(a2, bh, acc2, 0, 0, 0);  \
      acc3 = __builtin_amdgcn_mfma_f32_16x16x32_f16(a3, bh, acc3, 0, 0, 0);  \
    }                                                                        \
  } while (0)

  // ---- Prologue: meta(0), meta(1); window+issue i8(chunk 0) into bank A ----
  int4a mz0 = *(const int4a*)&meta[(pbase >> 6) * 4];
  int4a mz1 = *(const int4a*)&meta[((pbase + 64) >> 6) * 4];
  Bank bA, bB;
  ISSUE(bA, pbase + ssub * 16, mz0);

  floatx4 acc0 = {0,0,0,0}, acc1 = {0,0,0,0}, acc2 = {0,0,0,0}, acc3 = {0,0,0,0};

  // ---- Main loop, macro-unrolled: issue(c+1) | meta(c+2) | finish(c) |
  //      MFMA(c). Zero barriers -> prefetch stays in flight. ----
  // c = 0
  ISSUE(bB, pbase + 64 + ssub * 16, mz1);
  mz0 = *(const int4a*)&meta[((pbase + 128) >> 6) * 4];
  FINISH(bA, pbase + ssub * 16, 0);
  MFMA_STEP(0, 0);
  // c = 1
  ISSUE(bA, pbase + 128 + ssub * 16, mz0);
  mz1 = *(const int4a*)&meta[((pbase + 192) >> 6) * 4];
  FINISH(bB, pbase + 64 + ssub * 16, 1);
  MFMA_STEP(1, 1);
  // c = 2
  ISSUE(bB, pbase + 192 + ssub * 16, mz1);
  FINISH(bA, pbase + 128 + ssub * 16, 0);
  MFMA_STEP(2, 0);
  // c = 3
  FINISH(bB, pbase + 192 + ssub * 16, 1);
  MFMA_STEP(3, 1);

#undef ISSUE
#undef FINISH
#undef MFMA_STEP

  // ---- Epilogue: the ONLY barriers. All waves done with their tiles
  // before red (aliasing smem) is written. ----
  __syncthreads();

  const int mb = quad * 4;
#pragma unroll
  for (int i = 0; i < 4; ++i) red[wave * 1024 + (mb + i)      * 16 + ln] = acc0[i];
#pragma unroll
  for (int i = 0; i < 4; ++i) red[wave * 1024 + (16 + mb + i) * 16 + ln] = acc1[i];
#pragma unroll
  for (int i = 0; i < 4; ++i) red[wave * 1024 + (32 + mb + i) * 16 + ln] = acc2[i];
#pragma unroll
  for (int i = 0; i < 4; ++i) red[wave * 1024 + (48 + mb + i) * 16 + ln] = acc3[i];
  __syncthreads();

  // ---- Plain partial store ----
  float* pp = &part[(size_t)kq * OUTN];
#pragma unroll
  for (int c2 = 0; c2 < 4; ++c2) {
    const int cell = tid + c2 * 256;  // 1024 cells = 64 m x 16 n
    const int mm = cell >> 4, nn = cell & 15;
    pp[mm * OUTF + n0 + nn] =
        red[cell] + red[1024 + cell] + red[2048 + cell] + red[3072 + cell];
  }
}

// ---------------------------------------------------------------------------
// Reduce: out = sum_kq part[kq] + bias. 11.3 MB read + 2.8 MB write ~ 3 us.
// ---------------------------------------------------------------------------
__global__ __launch_bounds__(256) void reduce_kernel(
    const float* __restrict__ part, const float* __restrict__ bias,
    float* __restrict__ out) {
  const int t  = blockIdx.x * 256 + threadIdx.x;  // 688*256 = 176128 exact
  const int i4 = t * 4;
  floatx4 a = *(const floatx4*)&part[i4];
#pragma unroll
  for (int k = 1; k < KSPL; ++k) {
    const floatx4 b = *(const floatx4*)&part[(size_t)k * OUTN + i4];
    a[0] += b[0]; a[1] += b[1]; a[2] += b[2]; a[3] += b[3];
  }
  const int nn = i4 % OUTF;  // OUTF % 4 == 0: float4 never straddles rows
  const floatx4 bb = *(const floatx4*)&bias[nn];
  a[0] += bb[0]; a[1] += bb[1]; a[2] += bb[2]; a[3] += bb[3];
  *(floatx4*)&out[i4] = a;
}

// ---------------------------------------------------------------------------
// Inputs: 0 x(fp32) 1 int8_data(i32) 2 fp16_data(fp32) 3 scales(fp32)
// 4 bias(fp32) 5 int8_pos(UNUSED) 6 fp16_pos(i32) 7 block_idx(UNUSED)
// ws: x16 (512 KB) | meta (11.3 MB) | part (11.3 MB)
// ---------------------------------------------------------------------------
extern "C" void kernel_launch(void* const* d_in, const int* in_sizes, int n_in,
                              void* d_out, int out_size, void* d_ws,
                              size_t ws_size, hipStream_t stream) {
  const float* x      = (const float*)d_in[0];
  const int*   i8     = (const int*)d_in[1];
  const float* fpdat  = (const float*)d_in[2];
  const float* scales = (const float*)d_in[3];
  const float* bias   = (const float*)d_in[4];
  const int*   fppos  = (const int*)d_in[6];

  char* wsp = (char*)d_ws;
  _Float16* x16  = (_Float16*)wsp;
  int*      meta = (int*)(wsp + (size_t)TOK * INF * sizeof(_Float16));
  float*    part = (float*)(wsp + (size_t)TOK * INF * sizeof(_Float16)
                                + (size_t)NSLC * 16);
  float*    out  = (float*)d_out;

  const int n8 = in_sizes[1];
  const int nf = in_sizes[2];

  precompute_kernel<<<NSLC / 256, 256, 0, stream>>>(x, fppos, nf, x16, meta);
  gemm_fused<<<NBLK * KSPL, 256, 0, stream>>>(x16, i8, fpdat, scales, meta,
                                              part, n8);
  reduce_kernel<<<OUTN / (4 * 256), 256, 0, stream>>>(part, bias, out);
}

// Round 8
// 438.284 us; speedup vs baseline: 2.4919x; 1.0285x over previous
//
#include <hip/hip_runtime.h>
#include <hip/hip_fp16.h>

// Fixed problem shape
#define TOK   64
#define INF   4096
#define OUTF  11008
#define NUMEL (OUTF * INF)        // 45088768
#define NSLC  (NUMEL / 64)        // 704512 64-element slices
#define NBLK  (OUTF / 16)         // 688 N-tiles
#define KSPL  4                   // K-split -> 2752 blocks, K=1024 each
#define OUTN  (TOK * OUTF)        // 704512 output elems

// Harness dtypes: fp16 arrays arrive as fp32; ints as int32; output fp32.
typedef __attribute__((ext_vector_type(8))) _Float16 half8;
typedef __attribute__((ext_vector_type(4))) _Float16 half4;
typedef __attribute__((ext_vector_type(4))) float floatx4;
typedef __attribute__((ext_vector_type(4), aligned(4))) int int4u;   // dword-aligned dwordx4
typedef __attribute__((ext_vector_type(4))) int int4a;               // 16B-aligned dwordx4

// ---------------------------------------------------------------------------
// Precompute (unchanged): (a) x fp32 -> fp16 (512 KB, L2-resident GEMM A),
// (b) per-64-slice meta[s] = {c0 = lower_bound(fp16_pos, 64*s),
//     outlier mask lo, mask hi, pad} — one 16 B record.
// ---------------------------------------------------------------------------
__global__ __launch_bounds__(256) void precompute_kernel(
    const float* __restrict__ x, const int* __restrict__ fppos, int nf,
    _Float16* __restrict__ x16, int* __restrict__ meta) {
  const int t = blockIdx.x * 256 + threadIdx.x;
  if (t < (TOK * INF) / 4) {
    const floatx4 f = *(const floatx4*)&x[t * 4];
    half4 h;
    h[0] = (_Float16)f[0]; h[1] = (_Float16)f[1];
    h[2] = (_Float16)f[2]; h[3] = (_Float16)f[3];
    *(half4*)&x16[t * 4] = h;
  }
  if (t < NSLC) {
    const int target = t << 6;
    int lo = 0, hi = nf;
    while (lo < hi) {
      const int mid = (lo + hi) >> 1;
      if (fppos[mid] < target) lo = mid + 1; else hi = mid;
    }
    unsigned long long mask = 0ull;
    int j = lo;
    while (j < nf) {                 // mean 0.17 iters; P(>2) ~ 1e-4
      const int d = fppos[j] - target;
      if (d >= 64) break;
      mask |= 1ull << d;
      ++j;
    }
    int4a mv;
    mv[0] = lo;
    mv[1] = (int)(unsigned)(mask & 0xffffffffu);
    mv[2] = (int)(unsigned)(mask >> 32);
    mv[3] = 0;
    *(int4a*)&meta[t * 4] = mv;
  }
}

// ---------------------------------------------------------------------------
// meta_window1 (R3-verified verbatim): compacted i8 index i0 of position p0
// + 8-bit outlier window. off multiple of 8 -> never straddles halves.
// ---------------------------------------------------------------------------
__device__ __forceinline__ void meta_window1(const int p0, const int4a mv,
                                             int& i0, unsigned& m8) {
  const unsigned mlo = (unsigned)mv[1];
  const unsigned mhi = (unsigned)mv[2];
  const int off = p0 & 63;
  m8 = 0xffu & (off < 32 ? (mlo >> off) : (mhi >> (off - 32)));
  const unsigned bl = (off >= 32) ? mlo : (mlo & ((1u << off) - 1u));
  const unsigned bh = (off >= 32) ? (mhi & ((1u << (off - 32)) - 1u)) : 0u;
  i0 = p0 - mv[0] - (__popc(bl) + __popc(bh));
}

// ---------------------------------------------------------------------------
// finish_slot (R2-R7 verbatim): SLOW path only (>2 outliers in one 8-slot,
// ~1e-6 of slots; wave-uniformly skipped otherwise). Inline fpdat loads ok.
// ---------------------------------------------------------------------------
__device__ __forceinline__ half8 finish_slot(
    const unsigned m8, const int i0, const int p0, const float s,
    const int (&l)[8], const int* __restrict__ i8,
    const float* __restrict__ fpdat, const int n8) {
  const int f = (int)m8;
  float ov[8];
#pragma unroll
  for (int e = 0; e < 8; ++e) ov[e] = 0.f;
  if (f) {
    int fi = p0 - i0;  // c0 + (#outliers below p0)
#pragma unroll
    for (int e = 0; e < 8; ++e) {
      if ((f >> e) & 1) { ov[e] = fpdat[fi]; ++fi; }
    }
  }

  half8 oh;
  if (i0 + 8 <= n8) {
    if (f == 0) {
#pragma unroll
      for (int e = 0; e < 8; ++e) oh[e] = (_Float16)((float)l[e] * s);
    } else {
      int q = 0;
#pragma unroll
      for (int e = 0; e < 8; ++e) {
        const int flg = (f >> e) & 1;
        int lv = l[0];
#pragma unroll
        for (int qq = 1; qq < 8; ++qq) lv = (q == qq) ? l[qq] : lv;
        oh[e] = flg ? (_Float16)ov[e] : (_Float16)((float)lv * s);
        q += 1 - flg;
      }
    }
  } else {
    int c = 0;
    const int m = n8 - 1;
#pragma unroll
    for (int e = 0; e < 8; ++e) {
      const int flg = (f >> e) & 1;
      int idx = i0 + e - c;
      idx = idx < 0 ? 0 : (idx > m ? m : idx);
      oh[e] = flg ? (_Float16)ov[e] : (_Float16)((float)i8[idx] * s);
      c += flg;
    }
  }
  return oh;
}

// Per-chunk prefetch bank: everything the FIN_MFMA phase consumes, loaded one
// full iteration earlier. Direct array members only (R6 SROA lesson).
struct Pre {
  int la[8], lb[8];        // i8 dwords for the lane's two B fragment slots
  int i0a, i0b;
  unsigned m8a, m8b;
  float va0, va1, vb0, vb1;  // prefetched outlier values (rank 0,1 per slot)
  half8 A[8];              // A fragments: [st*4 + m] rows ln+16m, k st*32
};

// ---------------------------------------------------------------------------
// Fused GEMM v8 — no same-iteration load consumption anywhere.
// R1-R7 post-mortem: vmcnt is a FIFO count -> waiting on the NEWEST load
// (A-fragments loaded right before their MFMAs; fpdat loaded inside
// finish_slot) waits on everything older, draining the B prefetch queue
// every chunk regardless of barriers. v8: per chunk c the wave prefetches
// (into bank c&1, during iteration c-1): i8, outlier fpdat values (<=2 per
// slot; rarer -> wave-uniform-skipped slow path), and the A fragments.
// B is dequantized DIRECTLY into the MFMA B-operand (staging map == MFMA
// fragment map: lane ln owns row n0+ln, k quad*8 and quad*8+32), so the
// main loop has ZERO LDS, ZERO barriers, and only counted vmcnt waits on
// loads issued a full iteration earlier. LDS is epilogue-only (red, 16 KB).
// mfma_f32_16x16x32_f16 mapping + dequant numerics verified R1-R7.
// ---------------------------------------------------------------------------
__global__ __launch_bounds__(256, 3) void gemm_fused(
    const _Float16* __restrict__ x16, const int* __restrict__ i8,
    const float* __restrict__ fpdat, const float* __restrict__ scales,
    const int* __restrict__ meta, float* __restrict__ part,
    const int n8, const int nf) {
  __shared__ float red[4 * 64 * 16];  // 16 KB, epilogue only

  const int tid  = threadIdx.x;
  const int wave = tid >> 6;
  const int lane = tid & 63;
  const int quad = lane >> 4;
  const int ln   = lane & 15;
  const int nt   = blockIdx.x >> 2;
  const int kq   = blockIdx.x & 3;
  const int n0   = nt << 4;
  const int kbas = kq * 1024 + wave * 256;  // this wave's K base
  const int qoff = quad * 8;

  const int prow  = n0 + ln;
  const int pbase = prow * INF + kbas;      // positioned base of lane's row-K
  const float s   = scales[prow * 4 + kq];  // block-constant quant scale

#define ISSUE(BNK, CC, MV)                                                   \
  do {                                                                       \
    const int p0a_ = pbase + (CC) * 64 + qoff;                               \
    meta_window1(p0a_, (MV), BNK.i0a, BNK.m8a);                              \
    meta_window1(p0a_ + 32, (MV), BNK.i0b, BNK.m8b);                         \
    if (BNK.i0a + 8 <= n8) {                                                 \
      *(int4u*)&BNK.la[0] = *(const int4u*)&i8[BNK.i0a];                     \
      *(int4u*)&BNK.la[4] = *(const int4u*)&i8[BNK.i0a + 4];                 \
    }                                                                        \
    if (BNK.i0b + 8 <= n8) {                                                 \
      *(int4u*)&BNK.lb[0] = *(const int4u*)&i8[BNK.i0b];                     \
      *(int4u*)&BNK.lb[4] = *(const int4u*)&i8[BNK.i0b + 4];                 \
    }                                                                        \
    if (BNK.m8a) {                                                           \
      const int fia_ = p0a_ - BNK.i0a;                                       \
      BNK.va0 = fpdat[fia_];                                                 \
      BNK.va1 = fpdat[fia_ + 1 < nf ? fia_ + 1 : nf - 1];                    \
    }                                                                        \
    if (BNK.m8b) {                                                           \
      const int fib_ = p0a_ + 32 - BNK.i0b;                                  \
      BNK.vb0 = fpdat[fib_];                                                 \
      BNK.vb1 = fpdat[fib_ + 1 < nf ? fib_ + 1 : nf - 1];                    \
    }                                                                        \
    const _Float16* ap_ = &x16[ln * INF + kbas + (CC) * 64 + qoff];          \
    BNK.A[0] = *(const half8*)&ap_[0];                                       \
    BNK.A[1] = *(const half8*)&ap_[16 * INF];                                \
    BNK.A[2] = *(const half8*)&ap_[32 * INF];                                \
    BNK.A[3] = *(const half8*)&ap_[48 * INF];                                \
    BNK.A[4] = *(const half8*)&ap_[32];                                      \
    BNK.A[5] = *(const half8*)&ap_[16 * INF + 32];                           \
    BNK.A[6] = *(const half8*)&ap_[32 * INF + 32];                           \
    BNK.A[7] = *(const half8*)&ap_[48 * INF + 32];                           \
  } while (0)

// Fast register-only combine: <=2 outliers per slot use prefetched V0/V1 by
// rank; int values via the R7-proven q-walk select chain (all-constant idx).
#define FSLOT(OH, LARR, M8, I0, V0, V1)                                      \
  do {                                                                       \
    const int f_ = (int)(M8);                                                \
    if ((I0) + 8 <= n8) {                                                    \
      if (f_ == 0) {                                                         \
        _Pragma("unroll")                                                    \
        for (int e = 0; e < 8; ++e) OH[e] = (_Float16)((float)LARR[e] * s);  \
      } else {                                                               \
        int q_ = 0;                                                          \
        _Pragma("unroll")                                                    \
        for (int e = 0; e < 8; ++e) {                                        \
          const int flg = (f_ >> e) & 1;                                     \
          const int rank = __popc(f_ & ((1 << e) - 1));                      \
          const float fv = (rank == 0) ? (V0) : (V1);                        \
          int lv = LARR[0];                                                  \
          _Pragma("unroll")                                                  \
          for (int qq = 1; qq < 8; ++qq) lv = (q_ == qq) ? LARR[qq] : lv;    \
          OH[e] = flg ? (_Float16)fv : (_Float16)((float)lv * s);            \
          q_ += 1 - flg;                                                     \
        }                                                                    \
      }                                                                      \
    } else {                                                                 \
      int c_ = 0;                                                            \
      const int m_ = n8 - 1;                                                 \
      _Pragma("unroll")                                                      \
      for (int e = 0; e < 8; ++e) {                                          \
        const int flg = (f_ >> e) & 1;                                       \
        const int rank = __popc(f_ & ((1 << e) - 1));                        \
        const float fv = (rank == 0) ? (V0) : (V1);                          \
        int idx = (I0) + e - c_;                                             \
        idx = idx < 0 ? 0 : (idx > m_ ? m_ : idx);                           \
        OH[e] = flg ? (_Float16)fv : (_Float16)((float)i8[idx] * s);         \
        c_ += flg;                                                           \
      }                                                                      \
    }                                                                        \
  } while (0)

#define FIN_MFMA(BNK, CC)                                                    \
  do {                                                                       \
    const int p0a_ = pbase + (CC) * 64 + qoff;                               \
    half8 b0, b1;                                                            \
    FSLOT(b0, BNK.la, BNK.m8a, BNK.i0a, BNK.va0, BNK.va1);                   \
    FSLOT(b1, BNK.lb, BNK.m8b, BNK.i0b, BNK.vb0, BNK.vb1);                   \
    if (__any(__popc((int)BNK.m8a) > 2 || __popc((int)BNK.m8b) > 2)) {       \
      if (__popc((int)BNK.m8a) > 2)                                          \
        b0 = finish_slot(BNK.m8a, BNK.i0a, p0a_, s, BNK.la, i8, fpdat, n8);  \
      if (__popc((int)BNK.m8b) > 2)                                          \
        b1 = finish_slot(BNK.m8b, BNK.i0b, p0a_ + 32, s, BNK.lb,             \
                         i8, fpdat, n8);                                     \
    }                                                                        \
    acc0 = __builtin_amdgcn_mfma_f32_16x16x32_f16(BNK.A[0], b0, acc0, 0,0,0);\
    acc1 = __builtin_amdgcn_mfma_f32_16x16x32_f16(BNK.A[1], b0, acc1, 0,0,0);\
    acc2 = __builtin_amdgcn_mfma_f32_16x16x32_f16(BNK.A[2], b0, acc2, 0,0,0);\
    acc3 = __builtin_amdgcn_mfma_f32_16x16x32_f16(BNK.A[3], b0, acc3, 0,0,0);\
    acc0 = __builtin_amdgcn_mfma_f32_16x16x32_f16(BNK.A[4], b1, acc0, 0,0,0);\
    acc1 = __builtin_amdgcn_mfma_f32_16x16x32_f16(BNK.A[5], b1, acc1, 0,0,0);\
    acc2 = __builtin_amdgcn_mfma_f32_16x16x32_f16(BNK.A[6], b1, acc2, 0,0,0);\
    acc3 = __builtin_amdgcn_mfma_f32_16x16x32_f16(BNK.A[7], b1, acc3, 0,0,0);\
  } while (0)

  // ---- Prologue: meta(0), meta(1); full ISSUE of chunk 0 into bank A ----
  int4a mzA = *(const int4a*)&meta[(pbase >> 6) * 4];
  int4a mzB = *(const int4a*)&meta[((pbase + 64) >> 6) * 4];
  Pre pA, pB;
  ISSUE(pA, 0, mzA);

  floatx4 acc0 = {0,0,0,0}, acc1 = {0,0,0,0}, acc2 = {0,0,0,0}, acc3 = {0,0,0,0};

  // ---- Main loop, macro-unrolled. Every FIN_MFMA consumes only loads
  //      issued one full iteration earlier -> counted vmcnt, never drain. ----
  // c = 0
  ISSUE(pB, 1, mzB);
  mzA = *(const int4a*)&meta[((pbase + 128) >> 6) * 4];
  FIN_MFMA(pA, 0);
  // c = 1
  ISSUE(pA, 2, mzA);
  mzB = *(const int4a*)&meta[((pbase + 192) >> 6) * 4];
  FIN_MFMA(pB, 1);
  // c = 2
  ISSUE(pB, 3, mzB);
  FIN_MFMA(pA, 2);
  // c = 3
  FIN_MFMA(pB, 3);

#undef ISSUE
#undef FSLOT
#undef FIN_MFMA

  // ---- Epilogue: cross-wave reduce (only barriers in the kernel) ----
  const int mb = quad * 4;
#pragma unroll
  for (int i = 0; i < 4; ++i) red[wave * 1024 + (mb + i)      * 16 + ln] = acc0[i];
#pragma unroll
  for (int i = 0; i < 4; ++i) red[wave * 1024 + (16 + mb + i) * 16 + ln] = acc1[i];
#pragma unroll
  for (int i = 0; i < 4; ++i) red[wave * 1024 + (32 + mb + i) * 16 + ln] = acc2[i];
#pragma unroll
  for (int i = 0; i < 4; ++i) red[wave * 1024 + (48 + mb + i) * 16 + ln] = acc3[i];
  __syncthreads();

  // ---- Plain partial store ----
  float* pp = &part[(size_t)kq * OUTN];
#pragma unroll
  for (int c2 = 0; c2 < 4; ++c2) {
    const int cell = tid + c2 * 256;  // 1024 cells = 64 m x 16 n
    const int mm = cell >> 4, nn = cell & 15;
    pp[mm * OUTF + n0 + nn] =
        red[cell] + red[1024 + cell] + red[2048 + cell] + red[3072 + cell];
  }
}

// ---------------------------------------------------------------------------
// Reduce: out = sum_kq part[kq] + bias. 11.3 MB read + 2.8 MB write ~ 3 us.
// ---------------------------------------------------------------------------
__global__ __launch_bounds__(256) void reduce_kernel(
    const float* __restrict__ part, const float* __restrict__ bias,
    float* __restrict__ out) {
  const int t  = blockIdx.x * 256 + threadIdx.x;  // 688*256 = 176128 exact
  const int i4 = t * 4;
  floatx4 a = *(const floatx4*)&part[i4];
#pragma unroll
  for (int k = 1; k < KSPL; ++k) {
    const floatx4 b = *(const floatx4*)&part[(size_t)k * OUTN + i4];
    a[0] += b[0]; a[1] += b[1]; a[2] += b[2]; a[3] += b[3];
  }
  const int nn = i4 % OUTF;  // OUTF % 4 == 0: float4 never straddles rows
  const floatx4 bb = *(const floatx4*)&bias[nn];
  a[0] += bb[0]; a[1] += bb[1]; a[2] += bb[2]; a[3] += bb[3];
  *(floatx4*)&out[i4] = a;
}

// ---------------------------------------------------------------------------
// Inputs: 0 x(fp32) 1 int8_data(i32) 2 fp16_data(fp32) 3 scales(fp32)
// 4 bias(fp32) 5 int8_pos(UNUSED) 6 fp16_pos(i32) 7 block_idx(UNUSED)
// ws: x16 (512 KB) | meta (11.3 MB) | part (11.3 MB)
// ---------------------------------------------------------------------------
extern "C" void kernel_launch(void* const* d_in, const int* in_sizes, int n_in,
                              void* d_out, int out_size, void* d_ws,
                              size_t ws_size, hipStream_t stream) {
  const float* x      = (const float*)d_in[0];
  const int*   i8     = (const int*)d_in[1];
  const float* fpdat  = (const float*)d_in[2];
  const float* scales = (const float*)d_in[3];
  const float* bias   = (const float*)d_in[4];
  const int*   fppos  = (const int*)d_in[6];

  char* wsp = (char*)d_ws;
  _Float16* x16  = (_Float16*)wsp;
  int*      meta = (int*)(wsp + (size_t)TOK * INF * sizeof(_Float16));
  float*    part = (float*)(wsp + (size_t)TOK * INF * sizeof(_Float16)
                                + (size_t)NSLC * 16);
  float*    out  = (float*)d_out;

  const int n8 = in_sizes[1];
  const int nf = in_sizes[2];

  precompute_kernel<<<NSLC / 256, 256, 0, stream>>>(x, fppos, nf, x16, meta);
  gemm_fused<<<NBLK * KSPL, 256, 0, stream>>>(x16, i8, fpdat, scales, meta,
                                              part, n8, nf);
  reduce_kernel<<<OUTN / (4 * 256), 256, 0, stream>>>(part, bias, out);
}